// Round 5
// baseline (566.517 us; speedup 1.0000x reference)
//
#include <hip/hip_runtime.h>
#include <hip/hip_bf16.h>

#define B_      8
#define HH      32
#define WW      32
#define E_      256
#define HEADS_  8
#define KD_     32
#define FFN_    1024
#define NQ_     64
#define L_      1024
#define SCALING_ 0.17677669529663687f
#define EPS_    1e-6f

typedef short bf16x8 __attribute__((ext_vector_type(8)));
typedef float f32x4 __attribute__((ext_vector_type(4)));
typedef unsigned short ushort_t;

__device__ __forceinline__ ushort_t f2bf(float f) {
    __hip_bfloat16 h = __float2bfloat16(f);
    return *reinterpret_cast<ushort_t*>(&h);
}
__device__ __forceinline__ float bf2f(ushort_t u) {
    __hip_bfloat16 h = *reinterpret_cast<__hip_bfloat16*>(&u);
    return __bfloat162float(h);
}

// ---- fused depthwise 3x3 conv + residual + LayerNorm --------------------
__global__ void posconv_ln_kernel(const float* __restrict__ x, const float* __restrict__ w,
                                  const float* __restrict__ bias,
                                  const float* __restrict__ g, const float* __restrict__ bb,
                                  float* __restrict__ X, ushort_t* __restrict__ HN) {
    __shared__ float red[E_];
    int e = threadIdx.x;
    int l = blockIdx.x & (L_ - 1);
    int b = blockIdx.x >> 10;
    int hh = l >> 5, ww = l & 31;
    float acc = bias[e];
#pragma unroll
    for (int dh = -1; dh <= 1; ++dh) {
        int h2 = hh + dh; if (h2 < 0 || h2 >= HH) continue;
#pragma unroll
        for (int dw = -1; dw <= 1; ++dw) {
            int w2 = ww + dw; if (w2 < 0 || w2 >= WW) continue;
            acc += x[((b * HH + h2) * WW + w2) * E_ + e] *
                   w[e * 9 + (dh + 1) * 3 + (dw + 1)];
        }
    }
    float xv = x[(long)blockIdx.x * E_ + e] + acc;
    X[(long)blockIdx.x * E_ + e] = xv;
    red[e] = xv; __syncthreads();
    for (int s = 128; s > 0; s >>= 1) { if (e < s) red[e] += red[e + s]; __syncthreads(); }
    float mean = red[0] * (1.0f / E_); __syncthreads();
    float d = xv - mean;
    red[e] = d * d; __syncthreads();
    for (int s = 128; s > 0; s >>= 1) { if (e < s) red[e] += red[e + s]; __syncthreads(); }
    float var = red[0] * (1.0f / E_);
    HN[(long)blockIdx.x * E_ + e] = f2bf(d * rsqrtf(var + EPS_) * g[e] + bb[e]);
}

// ---- depthwise 5x5 conv (f32 in/out) ------------------------------------
__global__ void lepe_kernel(const float* __restrict__ v, const float* __restrict__ w,
                            const float* __restrict__ bias, float* __restrict__ out) {
    int e = threadIdx.x;
    int l = blockIdx.x & (L_ - 1);
    int b = blockIdx.x >> 10;
    int hh = l >> 5, ww = l & 31;
    float acc = bias[e];
#pragma unroll
    for (int dh = -2; dh <= 2; ++dh) {
        int h2 = hh + dh; if (h2 < 0 || h2 >= HH) continue;
#pragma unroll
        for (int dw = -2; dw <= 2; ++dw) {
            int w2 = ww + dw; if (w2 < 0 || w2 >= WW) continue;
            acc += v[((long)(b * HH + h2) * WW + w2) * E_ + e] *
                   w[e * 25 + (dh + 2) * 5 + (dw + 2)];
        }
    }
    out[(long)blockIdx.x * E_ + e] = acc;
}

// ---- LayerNorm f32 -> bf16 ----------------------------------------------
__global__ void ln_kernel(const float* __restrict__ x, const float* __restrict__ g,
                          const float* __restrict__ b, ushort_t* __restrict__ y) {
    __shared__ float red[E_];
    int tid = threadIdx.x;
    long row = blockIdx.x;
    float v = x[row * E_ + tid];
    red[tid] = v; __syncthreads();
    for (int s = 128; s > 0; s >>= 1) { if (tid < s) red[tid] += red[tid + s]; __syncthreads(); }
    float mean = red[0] * (1.0f / E_); __syncthreads();
    float d = v - mean;
    red[tid] = d * d; __syncthreads();
    for (int s = 128; s > 0; s >>= 1) { if (tid < s) red[tid] += red[tid + s]; __syncthreads(); }
    float var = red[0] * (1.0f / E_);
    y[row * E_ + tid] = f2bf(d * rsqrtf(var + EPS_) * g[tid] + b[tid]);
}

// ---- mask f32 -> bf16 (coalesced) ---------------------------------------
__global__ void maskcvt_kernel(const float* __restrict__ m, ushort_t* __restrict__ o) {
    long i = ((long)blockIdx.x * 256 + threadIdx.x) * 4;
    float4 v = *reinterpret_cast<const float4*>(m + i);
    uint2 p;
    p.x = (unsigned int)f2bf(v.x) | ((unsigned int)f2bf(v.y) << 16);
    p.y = (unsigned int)f2bf(v.z) | ((unsigned int)f2bf(v.w) << 16);
    *reinterpret_cast<uint2*>(o + i) = p;
}

// ---- fused QKV MFMA GEMM: BM=128 BN=64 BK=64, grid (64,12) ---------------
// QKV[m][768]: q(0..255, theta), k(256..511, theta+scale), v(512..767, + f32 Vb)
__global__ __launch_bounds__(256) void gemm_qkv(
        const ushort_t* __restrict__ A, const float* __restrict__ wq,
        const float* __restrict__ wk, const float* __restrict__ wv,
        const float* __restrict__ bqp, const float* __restrict__ bkp,
        const float* __restrict__ bvp, ushort_t* __restrict__ QKV,
        float* __restrict__ Vb, const float* __restrict__ sinp,
        const float* __restrict__ cosp) {
    __shared__ __align__(16) ushort_t As[128 * 72];
    __shared__ __align__(16) ushort_t Ws[64 * 72];
    int tid = threadIdx.x;
    int wave = tid >> 6, lane = tid & 63;
    int quad = lane >> 4, l16 = lane & 15;
    int wm = wave >> 1, wn = wave & 1;
    long mBase = (long)blockIdx.x * 128;
    int sel = blockIdx.y >> 2;
    const float* W = sel == 0 ? wq : (sel == 1 ? wk : wv);
    const float* bias = sel == 0 ? bqp : (sel == 1 ? bkp : bvp);
    int nLocBase = (blockIdx.y & 3) * 64;
    const int K = 256;

    f32x4 acc[4][2];
#pragma unroll
    for (int i = 0; i < 4; ++i)
#pragma unroll
        for (int j = 0; j < 2; ++j) acc[i][j] = (f32x4){0.f, 0.f, 0.f, 0.f};

    for (int kt0 = 0; kt0 < K; kt0 += 64) {
#pragma unroll
        for (int r = 0; r < 4; ++r) {
            int idx = tid + 256 * r;
            int row = idx >> 3, q = idx & 7;
            *reinterpret_cast<uint4*>(&As[row * 72 + q * 8]) =
                *reinterpret_cast<const uint4*>(A + (mBase + row) * (long)K + kt0 + q * 8);
        }
#pragma unroll
        for (int r = 0; r < 4; ++r) {
            int idx = tid + 256 * r;
            int row = idx >> 4, kq = idx & 15;
            float4 v = *reinterpret_cast<const float4*>(W + (nLocBase + row) * (long)K + kt0 + kq * 4);
            unsigned int p0 = f2bf(v.x) | ((unsigned int)f2bf(v.y) << 16);
            unsigned int p1 = f2bf(v.z) | ((unsigned int)f2bf(v.w) << 16);
            *reinterpret_cast<unsigned int*>(&Ws[row * 72 + kq * 4]) = p0;
            *reinterpret_cast<unsigned int*>(&Ws[row * 72 + kq * 4 + 2]) = p1;
        }
        __syncthreads();
#pragma unroll
        for (int kk = 0; kk < 2; ++kk) {
            bf16x8 af[4], bfr[2];
#pragma unroll
            for (int i = 0; i < 4; ++i)
                af[i] = *reinterpret_cast<const bf16x8*>(&As[(wm * 64 + i * 16 + l16) * 72 + kk * 32 + quad * 8]);
#pragma unroll
            for (int j = 0; j < 2; ++j)
                bfr[j] = *reinterpret_cast<const bf16x8*>(&Ws[(wn * 32 + j * 16 + l16) * 72 + kk * 32 + quad * 8]);
#pragma unroll
            for (int i = 0; i < 4; ++i)
#pragma unroll
                for (int j = 0; j < 2; ++j)
                    acc[i][j] = __builtin_amdgcn_mfma_f32_16x16x32_bf16(af[i], bfr[j], acc[i][j], 0, 0, 0);
        }
        __syncthreads();
    }

#pragma unroll
    for (int i = 0; i < 4; ++i)
#pragma unroll
        for (int j = 0; j < 2; ++j) {
            int nLoc = nLocBase + wn * 32 + j * 16 + l16;
            int nGlob = sel * 256 + nLoc;
            float bn = bias[nLoc];
#pragma unroll
            for (int r = 0; r < 4; ++r) {
                long m = mBase + wm * 64 + i * 16 + quad * 4 + r;
                float v = acc[i][j][r] + bn;
                if (sel == 1) v *= SCALING_;
                if (sel < 2) {
                    float other = __shfl_xor(v, 1);
                    int l = (int)(m & (L_ - 1));
                    int d = nLoc & 31;
                    float cc = cosp[l * 32 + d], ss = sinp[l * 32 + d];
                    v = v * cc + ((nLoc & 1) ? other : -other) * ss;
                }
                QKV[m * 768 + nGlob] = f2bf(v);
                if (sel == 2) Vb[m * 256 + nLoc] = v;
            }
        }
}

// ---- generic MFMA GEMM: BM=128 BN=64 BK=64 -------------------------------
template<int ABF16, int OBF16, int ACT, int SPLIT>
__global__ __launch_bounds__(256) void gemm_t(
        const void* __restrict__ Ap, const float* __restrict__ W,
        const float* __restrict__ bias, void* __restrict__ Cp,
        const float* __restrict__ resid, int M, int N, int K, float scale) {
    __shared__ __align__(16) ushort_t As[128 * 72];
    __shared__ __align__(16) ushort_t Ws[64 * 72];
    int tid = threadIdx.x;
    int wave = tid >> 6, lane = tid & 63;
    int quad = lane >> 4, l16 = lane & 15;
    int wm = wave >> 1, wn = wave & 1;
    long mBase = (long)blockIdx.x * 128;
    long nBase = (long)blockIdx.y * 64;

    f32x4 acc[4][2];
#pragma unroll
    for (int i = 0; i < 4; ++i)
#pragma unroll
        for (int j = 0; j < 2; ++j) acc[i][j] = (f32x4){0.f, 0.f, 0.f, 0.f};

    for (int kt0 = 0; kt0 < K; kt0 += 64) {
        if (ABF16) {
            const ushort_t* Ab = (const ushort_t*)Ap;
#pragma unroll
            for (int r = 0; r < 4; ++r) {
                int idx = tid + 256 * r;
                int row = idx >> 3, q = idx & 7;
                *reinterpret_cast<uint4*>(&As[row * 72 + q * 8]) =
                    *reinterpret_cast<const uint4*>(Ab + (mBase + row) * (long)K + kt0 + q * 8);
            }
        } else {
            const float* Af = (const float*)Ap;
#pragma unroll
            for (int r = 0; r < 8; ++r) {
                int idx = tid + 256 * r;
                int row = idx >> 4, kq = idx & 15;
                float4 v = *reinterpret_cast<const float4*>(Af + (mBase + row) * (long)K + kt0 + kq * 4);
                unsigned int p0 = f2bf(v.x) | ((unsigned int)f2bf(v.y) << 16);
                unsigned int p1 = f2bf(v.z) | ((unsigned int)f2bf(v.w) << 16);
                *reinterpret_cast<unsigned int*>(&As[row * 72 + kq * 4]) = p0;
                *reinterpret_cast<unsigned int*>(&As[row * 72 + kq * 4 + 2]) = p1;
            }
        }
#pragma unroll
        for (int r = 0; r < 4; ++r) {
            int idx = tid + 256 * r;
            int row = idx >> 4, kq = idx & 15;
            float4 v = *reinterpret_cast<const float4*>(W + (nBase + row) * (long)K + kt0 + kq * 4);
            unsigned int p0 = f2bf(v.x) | ((unsigned int)f2bf(v.y) << 16);
            unsigned int p1 = f2bf(v.z) | ((unsigned int)f2bf(v.w) << 16);
            *reinterpret_cast<unsigned int*>(&Ws[row * 72 + kq * 4]) = p0;
            *reinterpret_cast<unsigned int*>(&Ws[row * 72 + kq * 4 + 2]) = p1;
        }
        __syncthreads();
#pragma unroll
        for (int kk = 0; kk < 2; ++kk) {
            bf16x8 af[4], bfr[2];
#pragma unroll
            for (int i = 0; i < 4; ++i)
                af[i] = *reinterpret_cast<const bf16x8*>(&As[(wm * 64 + i * 16 + l16) * 72 + kk * 32 + quad * 8]);
#pragma unroll
            for (int j = 0; j < 2; ++j)
                bfr[j] = *reinterpret_cast<const bf16x8*>(&Ws[(wn * 32 + j * 16 + l16) * 72 + kk * 32 + quad * 8]);
#pragma unroll
            for (int i = 0; i < 4; ++i)
#pragma unroll
                for (int j = 0; j < 2; ++j)
                    acc[i][j] = __builtin_amdgcn_mfma_f32_16x16x32_bf16(af[i], bfr[j], acc[i][j], 0, 0, 0);
        }
        __syncthreads();
    }

#pragma unroll
    for (int i = 0; i < 4; ++i)
#pragma unroll
        for (int j = 0; j < 2; ++j) {
            long n = nBase + wn * 32 + j * 16 + l16;
            float bn = bias[n];
            float eff = (SPLIT && n >= 256) ? 1.0f : scale;
#pragma unroll
            for (int r = 0; r < 4; ++r) {
                long m = mBase + wm * 64 + i * 16 + quad * 4 + r;
                float v = (acc[i][j][r] + bn) * eff;
                if (ACT) v = 0.5f * v * (1.0f + erff(v * 0.70710678118654752f));
                if (OBF16) {
                    ((ushort_t*)Cp)[m * N + n] = f2bf(v);
                } else {
                    if (resid) v += resid[m * N + n];
                    ((float*)Cp)[m * N + n] = v;
                }
            }
        }
}

// ---- MFMA flash attention ------------------------------------------------
// grid (qt, h, b); 4 waves x 16 queries. Q/K/V bf16 with row strides.
__global__ __launch_bounds__(256) void attn_mfma(
        const ushort_t* __restrict__ Q, int qs,
        const ushort_t* __restrict__ K, int ks,
        const ushort_t* __restrict__ V, int vs,
        const ushort_t* __restrict__ maskbf,
        const float* __restrict__ lepe, ushort_t* __restrict__ out, int nq) {
    __shared__ __align__(16) ushort_t Vt[32 * 136];
    __shared__ __align__(16) ushort_t Pl[4][16 * 136];
    __shared__ __align__(16) ushort_t Ml[64 * 136];
    int tid = threadIdx.x;
    int wave = tid >> 6, lane = tid & 63;
    int quad = lane >> 4, l16 = lane & 15;
    int qt = blockIdx.x, h = blockIdx.y, b = blockIdx.z;
    int qbase = qt * 64 + wave * 16;

    bf16x8 qfrag = *reinterpret_cast<const bf16x8*>(
        Q + ((long)b * nq + qbase + l16) * qs + h * KD_ + quad * 8);

    f32x4 acc_o[2];
    acc_o[0] = (f32x4){0.f, 0.f, 0.f, 0.f};
    acc_o[1] = (f32x4){0.f, 0.f, 0.f, 0.f};
    float lsum[4] = {0.f, 0.f, 0.f, 0.f};

    int kp = tid & 63;
    int dq = tid >> 6;

    for (int kb = 0; kb < L_; kb += 128) {
        __syncthreads();
        {   // stage V transposed: Vt[d][key]
            const ushort_t* vp = V + ((long)b * L_ + kb + 2 * kp) * vs + h * KD_ + dq * 8;
            uint4 ua = *reinterpret_cast<const uint4*>(vp);
            uint4 ub = *reinterpret_cast<const uint4*>(vp + vs);
            const unsigned int* wa = reinterpret_cast<const unsigned int*>(&ua);
            const unsigned int* wb = reinterpret_cast<const unsigned int*>(&ub);
#pragma unroll
            for (int i = 0; i < 8; ++i) {
                unsigned int a16 = (wa[i >> 1] >> ((i & 1) * 16)) & 0xFFFF;
                unsigned int b16 = (wb[i >> 1] >> ((i & 1) * 16)) & 0xFFFF;
                *reinterpret_cast<unsigned int*>(&Vt[(dq * 8 + i) * 136 + 2 * kp]) =
                    a16 | (b16 << 16);
            }
        }
        if (maskbf) {  // stage mask tile [64 q][128 k]
#pragma unroll
            for (int r = 0; r < 4; ++r) {
                int idx = tid + 256 * r;
                int row = idx >> 4, c = idx & 15;
                *reinterpret_cast<uint4*>(&Ml[row * 136 + c * 8]) =
                    *reinterpret_cast<const uint4*>(
                        &maskbf[((long)h * L_ + qt * 64 + row) * L_ + kb + c * 8]);
            }
        }
        __syncthreads();

        // S phase
        for (int kt = 0; kt < 8; ++kt) {
            bf16x8 kf = *reinterpret_cast<const bf16x8*>(
                K + ((long)b * L_ + kb + kt * 16 + l16) * ks + h * KD_ + quad * 8);
            f32x4 sa;
            if (maskbf) {
#pragma unroll
                for (int r = 0; r < 4; ++r)
                    sa[r] = bf2f(Ml[(wave * 16 + quad * 4 + r) * 136 + kt * 16 + l16]);
            } else {
                sa = (f32x4){0.f, 0.f, 0.f, 0.f};
            }
            sa = __builtin_amdgcn_mfma_f32_16x16x32_bf16(qfrag, kf, sa, 0, 0, 0);
#pragma unroll
            for (int r = 0; r < 4; ++r) {
                float p = __expf(sa[r]);
                lsum[r] += p;
                Pl[wave][(quad * 4 + r) * 136 + kt * 16 + l16] = f2bf(p);
            }
        }

        // PV phase
#pragma unroll
        for (int c = 0; c < 4; ++c) {
            bf16x8 pa = *reinterpret_cast<const bf16x8*>(
                &Pl[wave][l16 * 136 + c * 32 + quad * 8]);
#pragma unroll
            for (int dt = 0; dt < 2; ++dt) {
                bf16x8 vf = *reinterpret_cast<const bf16x8*>(
                    &Vt[(dt * 16 + l16) * 136 + c * 32 + quad * 8]);
                acc_o[dt] = __builtin_amdgcn_mfma_f32_16x16x32_bf16(pa, vf, acc_o[dt], 0, 0, 0);
            }
        }
    }

#pragma unroll
    for (int off = 1; off < 16; off <<= 1) {
#pragma unroll
        for (int r = 0; r < 4; ++r) lsum[r] += __shfl_xor(lsum[r], off);
    }

#pragma unroll
    for (int dt = 0; dt < 2; ++dt)
#pragma unroll
        for (int r = 0; r < 4; ++r) {
            float v = acc_o[dt][r] / lsum[r];
            long oi = ((long)b * nq + qbase + quad * 4 + r) * E_ + h * KD_ + dt * 16 + l16;
            if (lepe) v += lepe[oi];
            out[oi] = f2bf(v);
        }
}

extern "C" void kernel_launch(void* const* d_in, const int* in_sizes, int n_in,
                              void* d_out, int out_size, void* d_ws, size_t ws_size,
                              hipStream_t stream) {
    const float* x        = (const float*)d_in[0];
    const float* queries  = (const float*)d_in[1];
    const float* sinp     = (const float*)d_in[2];
    const float* cosp     = (const float*)d_in[3];
    const float* mask     = (const float*)d_in[4];
    const float* ln1_g    = (const float*)d_in[5];
    const float* ln1_b    = (const float*)d_in[6];
    const float* ln2_g    = (const float*)d_in[7];
    const float* ln2_b    = (const float*)d_in[8];
    const float* wq       = (const float*)d_in[9];
    const float* bq       = (const float*)d_in[10];
    const float* wk       = (const float*)d_in[11];
    const float* bk       = (const float*)d_in[12];
    const float* wv       = (const float*)d_in[13];
    const float* bv       = (const float*)d_in[14];
    const float* lepe_w   = (const float*)d_in[15];
    const float* lepe_b   = (const float*)d_in[16];
    const float* wo       = (const float*)d_in[17];
    const float* bo       = (const float*)d_in[18];
    const float* fc1_w    = (const float*)d_in[19];
    const float* fc1_b    = (const float*)d_in[20];
    const float* fc2_w    = (const float*)d_in[21];
    const float* fc2_b    = (const float*)d_in[22];
    const float* pos_w    = (const float*)d_in[23];
    const float* pos_b    = (const float*)d_in[24];
    const float* ca_in_w  = (const float*)d_in[25];
    const float* ca_in_b  = (const float*)d_in[26];
    const float* ca_out_w = (const float*)d_in[27];
    const float* ca_out_b = (const float*)d_in[28];

    float* ws = (float*)d_ws;
    const long SZ = (long)B_ * L_ * E_;       // 2,097,152
    float* X    = ws;                 // f32
    float* Vb   = ws + SZ;            // f32
    float* LEP  = ws + 2 * SZ;        // f32; Q2 alias after attn
    float* Q2   = LEP;
    ushort_t* U = (ushort_t*)(ws + 3 * SZ);
    ushort_t* QKV_u = U;              // 3*SZ ushorts (8192 x 768)
    ushort_t* T_u   = U + 3 * SZ;     // SZ ushorts: HN1 / ATT / HN2 / CA small
    ushort_t* HID_u = U + 4 * SZ;     // 4*SZ ushorts (8192 x 1024); MB alias
    ushort_t* MB_u  = HID_u;          // bf16 mask 8M (used before fc1)
    // CA aliases:
    ushort_t* QLN_u  = T_u;
    ushort_t* QP_u   = T_u + 131072;
    ushort_t* CAO_u  = T_u + 262144;
    ushort_t* QHID_u = T_u + 458752;  // 512*1024, fits in 2M region
    ushort_t* KV_u   = QKV_u;         // 8192 x 512

    float* XOUT = (float*)d_out;
    float* QOUT = (float*)d_out + 2097152;

    dim3 blk(256);
    const int rows = B_ * L_;  // 8192

    // ---- main path ----
    posconv_ln_kernel<<<rows, blk, 0, stream>>>(x, pos_w, pos_b, ln1_g, ln1_b, X, T_u);
    maskcvt_kernel<<<8192, blk, 0, stream>>>(mask, MB_u);
    gemm_qkv<<<dim3(64, 12), blk, 0, stream>>>(T_u, wq, wk, wv, bq, bk, bv, QKV_u, Vb, sinp, cosp);
    lepe_kernel<<<rows, blk, 0, stream>>>(Vb, lepe_w, lepe_b, LEP);
    attn_mfma<<<dim3(16, 8, 8), blk, 0, stream>>>(QKV_u, 768, QKV_u + 256, 768, QKV_u + 512, 768,
                                                  MB_u, LEP, T_u, L_);
    gemm_t<1,0,0,0><<<dim3(64, 4), blk, 0, stream>>>(T_u, wo, bo, X, X, rows, 256, 256, 1.0f);
    ln_kernel<<<rows, blk, 0, stream>>>(X, ln2_g, ln2_b, T_u);
    gemm_t<1,1,1,0><<<dim3(64, 16), blk, 0, stream>>>(T_u, fc1_w, fc1_b, HID_u, nullptr, rows, 1024, 256, 1.0f);
    gemm_t<1,0,0,0><<<dim3(64, 4), blk, 0, stream>>>(HID_u, fc2_w, fc2_b, XOUT, X, rows, 256, 1024, 1.0f);

    // ---- cross-attention path ----
    ln_kernel<<<B_ * NQ_, blk, 0, stream>>>(queries, ln1_g, ln1_b, QLN_u);
    gemm_t<1,1,0,0><<<dim3(4, 4), blk, 0, stream>>>(QLN_u, ca_in_w, ca_in_b, QP_u, nullptr, 512, 256, 256, 1.0f);
    gemm_t<0,1,0,1><<<dim3(64, 8), blk, 0, stream>>>(XOUT, ca_in_w + 65536, ca_in_b + 256, KV_u, nullptr,
                                                     rows, 512, 256, SCALING_);
    attn_mfma<<<dim3(1, 8, 8), blk, 0, stream>>>(QP_u, 256, KV_u, 512, KV_u + 256, 512,
                                                 nullptr, nullptr, CAO_u, NQ_);
    gemm_t<1,0,0,0><<<dim3(4, 4), blk, 0, stream>>>(CAO_u, ca_out_w, ca_out_b, Q2, queries, 512, 256, 256, 1.0f);
    ln_kernel<<<B_ * NQ_, blk, 0, stream>>>(Q2, ln2_g, ln2_b, QLN_u);
    gemm_t<1,1,1,0><<<dim3(4, 16), blk, 0, stream>>>(QLN_u, fc1_w, fc1_b, QHID_u, nullptr, 512, 1024, 256, 1.0f);
    gemm_t<1,0,0,0><<<dim3(4, 4), blk, 0, stream>>>(QHID_u, fc2_w, fc2_b, QOUT, Q2, 512, 256, 1024, 1.0f);
}

// Round 6
// 436.796 us; speedup vs baseline: 1.2970x; 1.2970x over previous
//
#include <hip/hip_runtime.h>
#include <hip/hip_bf16.h>

#define B_      8
#define HH      32
#define WW      32
#define E_      256
#define HEADS_  8
#define KD_     32
#define FFN_    1024
#define NQ_     64
#define L_      1024
#define SCALING_ 0.17677669529663687f
#define EPS_    1e-6f

typedef short bf16x8 __attribute__((ext_vector_type(8)));
typedef float f32x4 __attribute__((ext_vector_type(4)));
typedef unsigned short ushort_t;

__device__ __forceinline__ ushort_t f2bf(float f) {
    __hip_bfloat16 h = __float2bfloat16(f);
    return *reinterpret_cast<ushort_t*>(&h);
}
__device__ __forceinline__ float bf2f(ushort_t u) {
    __hip_bfloat16 h = *reinterpret_cast<__hip_bfloat16*>(&u);
    return __bfloat162float(h);
}

// ---- fused depthwise 3x3 conv + residual + LayerNorm --------------------
__global__ void posconv_ln_kernel(const float* __restrict__ x, const float* __restrict__ w,
                                  const float* __restrict__ bias,
                                  const float* __restrict__ g, const float* __restrict__ bb,
                                  float* __restrict__ X, ushort_t* __restrict__ HN) {
    __shared__ float red[E_];
    int e = threadIdx.x;
    int l = blockIdx.x & (L_ - 1);
    int b = blockIdx.x >> 10;
    int hh = l >> 5, ww = l & 31;
    float acc = bias[e];
#pragma unroll
    for (int dh = -1; dh <= 1; ++dh) {
        int h2 = hh + dh; if (h2 < 0 || h2 >= HH) continue;
#pragma unroll
        for (int dw = -1; dw <= 1; ++dw) {
            int w2 = ww + dw; if (w2 < 0 || w2 >= WW) continue;
            acc += x[((b * HH + h2) * WW + w2) * E_ + e] *
                   w[e * 9 + (dh + 1) * 3 + (dw + 1)];
        }
    }
    float xv = x[(long)blockIdx.x * E_ + e] + acc;
    X[(long)blockIdx.x * E_ + e] = xv;
    red[e] = xv; __syncthreads();
    for (int s = 128; s > 0; s >>= 1) { if (e < s) red[e] += red[e + s]; __syncthreads(); }
    float mean = red[0] * (1.0f / E_); __syncthreads();
    float d = xv - mean;
    red[e] = d * d; __syncthreads();
    for (int s = 128; s > 0; s >>= 1) { if (e < s) red[e] += red[e + s]; __syncthreads(); }
    float var = red[0] * (1.0f / E_);
    HN[(long)blockIdx.x * E_ + e] = f2bf(d * rsqrtf(var + EPS_) * g[e] + bb[e]);
}

// ---- depthwise 5x5 conv (f32 in/out) ------------------------------------
__global__ void lepe_kernel(const float* __restrict__ v, const float* __restrict__ w,
                            const float* __restrict__ bias, float* __restrict__ out) {
    int e = threadIdx.x;
    int l = blockIdx.x & (L_ - 1);
    int b = blockIdx.x >> 10;
    int hh = l >> 5, ww = l & 31;
    float acc = bias[e];
#pragma unroll
    for (int dh = -2; dh <= 2; ++dh) {
        int h2 = hh + dh; if (h2 < 0 || h2 >= HH) continue;
#pragma unroll
        for (int dw = -2; dw <= 2; ++dw) {
            int w2 = ww + dw; if (w2 < 0 || w2 >= WW) continue;
            acc += v[((long)(b * HH + h2) * WW + w2) * E_ + e] *
                   w[e * 25 + (dh + 2) * 5 + (dw + 2)];
        }
    }
    out[(long)blockIdx.x * E_ + e] = acc;
}

// ---- LayerNorm f32 -> bf16 ----------------------------------------------
__global__ void ln_kernel(const float* __restrict__ x, const float* __restrict__ g,
                          const float* __restrict__ b, ushort_t* __restrict__ y) {
    __shared__ float red[E_];
    int tid = threadIdx.x;
    long row = blockIdx.x;
    float v = x[row * E_ + tid];
    red[tid] = v; __syncthreads();
    for (int s = 128; s > 0; s >>= 1) { if (tid < s) red[tid] += red[tid + s]; __syncthreads(); }
    float mean = red[0] * (1.0f / E_); __syncthreads();
    float d = v - mean;
    red[tid] = d * d; __syncthreads();
    for (int s = 128; s > 0; s >>= 1) { if (tid < s) red[tid] += red[tid + s]; __syncthreads(); }
    float var = red[0] * (1.0f / E_);
    y[row * E_ + tid] = f2bf(d * rsqrtf(var + EPS_) * g[tid] + b[tid]);
}

// ---- mask f32 -> bf16 (coalesced) ---------------------------------------
__global__ void maskcvt_kernel(const float* __restrict__ m, ushort_t* __restrict__ o) {
    long i = ((long)blockIdx.x * 256 + threadIdx.x) * 4;
    float4 v = *reinterpret_cast<const float4*>(m + i);
    uint2 p;
    p.x = (unsigned int)f2bf(v.x) | ((unsigned int)f2bf(v.y) << 16);
    p.y = (unsigned int)f2bf(v.z) | ((unsigned int)f2bf(v.w) << 16);
    *reinterpret_cast<uint2*>(o + i) = p;
}

// ---- convert all weights to bf16 once -----------------------------------
struct WTab { const float* src[8]; };
__global__ void wconv_kernel(WTab t, ushort_t* __restrict__ dst) {
    const int off[9] = {0, 65536, 131072, 196608, 262144, 524288, 786432, 983040, 1048576};
    long base = ((long)blockIdx.x * 256 + threadIdx.x) * 4;
    int r = 0;
#pragma unroll
    for (int i = 1; i < 8; ++i) r = (base >= off[i]) ? i : r;
    const float* s =
        r == 0 ? t.src[0] : r == 1 ? t.src[1] : r == 2 ? t.src[2] : r == 3 ? t.src[3] :
        r == 4 ? t.src[4] : r == 5 ? t.src[5] : r == 6 ? t.src[6] : t.src[7];
    float4 v = *reinterpret_cast<const float4*>(s + (base - off[r]));
    uint2 p;
    p.x = (unsigned int)f2bf(v.x) | ((unsigned int)f2bf(v.y) << 16);
    p.y = (unsigned int)f2bf(v.z) | ((unsigned int)f2bf(v.w) << 16);
    *reinterpret_cast<uint2*>(dst + base) = p;
}

// ---- MFMA GEMM v2: BM=64 BN=64 BK=64, bf16 A & W, register prefetch -----
// v = (acc + bias[n]); if n<scaleN v*=scale; THETA; ACT; +resid; ->Cf/Cb
template<int ACT, int THETA>
__global__ __launch_bounds__(256) void gemm2(
        const ushort_t* __restrict__ A, const ushort_t* __restrict__ W,
        const float* __restrict__ bias, ushort_t* __restrict__ Cb,
        float* __restrict__ Cf, const float* __restrict__ resid,
        int M, int N, int K, float scale, int scaleN,
        const float* __restrict__ sinp, const float* __restrict__ cosp) {
    __shared__ __align__(16) ushort_t As[64 * 72];
    __shared__ __align__(16) ushort_t Ws[64 * 72];
    int tid = threadIdx.x;
    int wave = tid >> 6, lane = tid & 63;
    int quad = lane >> 4, l16 = lane & 15;
    int wm = wave >> 1, wn = wave & 1;
    long mBase = (long)blockIdx.x * 64;
    long nBase = (long)blockIdx.y * 64;
    int row = tid >> 3, q = tid & 7;          // staging: idx = tid + 256*r
    int row2 = (tid + 256) >> 3, q2 = (tid + 256) & 7;

    f32x4 acc[2][2];
#pragma unroll
    for (int i = 0; i < 2; ++i)
#pragma unroll
        for (int j = 0; j < 2; ++j) acc[i][j] = (f32x4){0.f, 0.f, 0.f, 0.f};

    int nT = K >> 6;
    uint4 a0 = *reinterpret_cast<const uint4*>(A + (mBase + row) * (long)K + q * 8);
    uint4 a1 = *reinterpret_cast<const uint4*>(A + (mBase + row2) * (long)K + q2 * 8);
    uint4 w0 = *reinterpret_cast<const uint4*>(W + (nBase + row) * (long)K + q * 8);
    uint4 w1 = *reinterpret_cast<const uint4*>(W + (nBase + row2) * (long)K + q2 * 8);

    for (int t = 0; t < nT; ++t) {
        *reinterpret_cast<uint4*>(&As[row * 72 + q * 8]) = a0;
        *reinterpret_cast<uint4*>(&As[row2 * 72 + q2 * 8]) = a1;
        *reinterpret_cast<uint4*>(&Ws[row * 72 + q * 8]) = w0;
        *reinterpret_cast<uint4*>(&Ws[row2 * 72 + q2 * 8]) = w1;
        __syncthreads();
        if (t + 1 < nT) {
            int kt = (t + 1) << 6;
            a0 = *reinterpret_cast<const uint4*>(A + (mBase + row) * (long)K + kt + q * 8);
            a1 = *reinterpret_cast<const uint4*>(A + (mBase + row2) * (long)K + kt + q2 * 8);
            w0 = *reinterpret_cast<const uint4*>(W + (nBase + row) * (long)K + kt + q * 8);
            w1 = *reinterpret_cast<const uint4*>(W + (nBase + row2) * (long)K + kt + q2 * 8);
        }
#pragma unroll
        for (int kk = 0; kk < 2; ++kk) {
            bf16x8 af[2], bfr[2];
#pragma unroll
            for (int i = 0; i < 2; ++i)
                af[i] = *reinterpret_cast<const bf16x8*>(&As[(wm * 32 + i * 16 + l16) * 72 + kk * 32 + quad * 8]);
#pragma unroll
            for (int j = 0; j < 2; ++j)
                bfr[j] = *reinterpret_cast<const bf16x8*>(&Ws[(wn * 32 + j * 16 + l16) * 72 + kk * 32 + quad * 8]);
#pragma unroll
            for (int i = 0; i < 2; ++i)
#pragma unroll
                for (int j = 0; j < 2; ++j)
                    acc[i][j] = __builtin_amdgcn_mfma_f32_16x16x32_bf16(af[i], bfr[j], acc[i][j], 0, 0, 0);
        }
        __syncthreads();
    }

#pragma unroll
    for (int i = 0; i < 2; ++i)
#pragma unroll
        for (int j = 0; j < 2; ++j) {
            long n = nBase + wn * 32 + j * 16 + l16;
            float bn = bias[n];
            float eff = (n < scaleN) ? scale : 1.0f;
#pragma unroll
            for (int r = 0; r < 4; ++r) {
                long m = mBase + wm * 32 + i * 16 + quad * 4 + r;
                float v = (acc[i][j][r] + bn) * eff;
                if (THETA) {
                    float other = __shfl_xor(v, 1);
                    int l = (int)(m & (L_ - 1));
                    int d = (int)(n & 31);
                    float cc = cosp[l * 32 + d], ss = sinp[l * 32 + d];
                    v = v * cc + ((n & 1) ? other : -other) * ss;
                }
                if (ACT) v = 0.5f * v * (1.0f + erff(v * 0.70710678118654752f));
                if (resid) v += resid[m * N + n];
                if (Cf) Cf[m * N + n] = v;
                if (Cb) Cb[m * N + n] = f2bf(v);
            }
        }
}

// ---- MFMA flash attention v3: double-buffered Vt, direct mask loads -----
// grid (qt, h, b); 4 waves x 16 queries; 8 key-blocks of 128.
__global__ __launch_bounds__(256) void attn3(
        const ushort_t* __restrict__ Q, int qs,
        const ushort_t* __restrict__ K, int ks,
        const ushort_t* __restrict__ V, int vs,
        const ushort_t* __restrict__ maskbf,
        const float* __restrict__ lepe, ushort_t* __restrict__ out, int nq) {
    __shared__ __align__(16) ushort_t Vt[2][32 * 136];
    __shared__ __align__(16) ushort_t Pl[4][16 * 136];
    int tid = threadIdx.x;
    int wave = tid >> 6, lane = tid & 63;
    int quad = lane >> 4, l16 = lane & 15;
    int qt = blockIdx.x, h = blockIdx.y, b = blockIdx.z;
    int qbase = qt * 64 + wave * 16;

    bf16x8 qfrag = *reinterpret_cast<const bf16x8*>(
        Q + ((long)b * nq + qbase + l16) * qs + h * KD_ + quad * 8);

    f32x4 acc_o[2];
    acc_o[0] = (f32x4){0.f, 0.f, 0.f, 0.f};
    acc_o[1] = (f32x4){0.f, 0.f, 0.f, 0.f};
    float lsum[4] = {0.f, 0.f, 0.f, 0.f};

    int kp = tid & 63;   // key pair for V staging
    int dq = tid >> 6;   // d-octet

    // preload V tile 0 into regs
    const ushort_t* vp = V + ((long)b * L_ + 2 * kp) * vs + h * KD_ + dq * 8;
    uint4 ua = *reinterpret_cast<const uint4*>(vp);
    uint4 ub = *reinterpret_cast<const uint4*>(vp + vs);
    {
        const unsigned int* wa = reinterpret_cast<const unsigned int*>(&ua);
        const unsigned int* wb = reinterpret_cast<const unsigned int*>(&ub);
#pragma unroll
        for (int i = 0; i < 8; ++i) {
            unsigned int x16 = (wa[i >> 1] >> ((i & 1) * 16)) & 0xFFFF;
            unsigned int y16 = (wb[i >> 1] >> ((i & 1) * 16)) & 0xFFFF;
            *reinterpret_cast<unsigned int*>(&Vt[0][(dq * 8 + i) * 136 + 2 * kp]) =
                x16 | (y16 << 16);
        }
    }

    for (int it = 0; it < 8; ++it) {
        int kb = it * 128;
        __syncthreads();   // Vt[it&1] visible; all waves done with it-1
        if (it < 7) {      // load next V tile into regs (hidden under compute)
            const ushort_t* vn = V + ((long)b * L_ + kb + 128 + 2 * kp) * vs + h * KD_ + dq * 8;
            ua = *reinterpret_cast<const uint4*>(vn);
            ub = *reinterpret_cast<const uint4*>(vn + vs);
        }

        // S phase: two groups of 4 key-tiles with prefetched K frags
#pragma unroll
        for (int g = 0; g < 2; ++g) {
            bf16x8 kf[4];
#pragma unroll
            for (int kt = 0; kt < 4; ++kt)
                kf[kt] = *reinterpret_cast<const bf16x8*>(
                    K + ((long)b * L_ + kb + (g * 4 + kt) * 16 + l16) * ks + h * KD_ + quad * 8);
#pragma unroll
            for (int kt = 0; kt < 4; ++kt) {
                int kcol = (g * 4 + kt) * 16;
                f32x4 sa;
                if (maskbf) {
#pragma unroll
                    for (int r = 0; r < 4; ++r)
                        sa[r] = bf2f(maskbf[((long)h * L_ + qbase + quad * 4 + r) * L_ + kb + kcol + l16]);
                } else {
                    sa = (f32x4){0.f, 0.f, 0.f, 0.f};
                }
                sa = __builtin_amdgcn_mfma_f32_16x16x32_bf16(qfrag, kf[kt], sa, 0, 0, 0);
#pragma unroll
                for (int r = 0; r < 4; ++r) {
                    float p = __expf(sa[r]);
                    lsum[r] += p;
                    Pl[wave][(quad * 4 + r) * 136 + kcol + l16] = f2bf(p);
                }
            }
        }

        // PV phase (reads Vt[it&1] + own-wave Pl)
#pragma unroll
        for (int c = 0; c < 4; ++c) {
            bf16x8 pa = *reinterpret_cast<const bf16x8*>(
                &Pl[wave][l16 * 136 + c * 32 + quad * 8]);
#pragma unroll
            for (int dt = 0; dt < 2; ++dt) {
                bf16x8 vf = *reinterpret_cast<const bf16x8*>(
                    &Vt[it & 1][(dt * 16 + l16) * 136 + c * 32 + quad * 8]);
                acc_o[dt] = __builtin_amdgcn_mfma_f32_16x16x32_bf16(pa, vf, acc_o[dt], 0, 0, 0);
            }
        }

        if (it < 7) {   // write next Vt buffer (safe: barrier at loop top)
            const unsigned int* wa = reinterpret_cast<const unsigned int*>(&ua);
            const unsigned int* wb = reinterpret_cast<const unsigned int*>(&ub);
#pragma unroll
            for (int i = 0; i < 8; ++i) {
                unsigned int x16 = (wa[i >> 1] >> ((i & 1) * 16)) & 0xFFFF;
                unsigned int y16 = (wb[i >> 1] >> ((i & 1) * 16)) & 0xFFFF;
                *reinterpret_cast<unsigned int*>(&Vt[(it + 1) & 1][(dq * 8 + i) * 136 + 2 * kp]) =
                    x16 | (y16 << 16);
            }
        }
    }

#pragma unroll
    for (int off = 1; off < 16; off <<= 1) {
#pragma unroll
        for (int r = 0; r < 4; ++r) lsum[r] += __shfl_xor(lsum[r], off);
    }

#pragma unroll
    for (int dt = 0; dt < 2; ++dt)
#pragma unroll
        for (int r = 0; r < 4; ++r) {
            float v = acc_o[dt][r] / lsum[r];
            long oi = ((long)b * nq + qbase + quad * 4 + r) * E_ + h * KD_ + dt * 16 + l16;
            if (lepe) v += lepe[oi];
            out[oi] = f2bf(v);
        }
}

extern "C" void kernel_launch(void* const* d_in, const int* in_sizes, int n_in,
                              void* d_out, int out_size, void* d_ws, size_t ws_size,
                              hipStream_t stream) {
    const float* x        = (const float*)d_in[0];
    const float* queries  = (const float*)d_in[1];
    const float* sinp     = (const float*)d_in[2];
    const float* cosp     = (const float*)d_in[3];
    const float* mask     = (const float*)d_in[4];
    const float* ln1_g    = (const float*)d_in[5];
    const float* ln1_b    = (const float*)d_in[6];
    const float* ln2_g    = (const float*)d_in[7];
    const float* ln2_b    = (const float*)d_in[8];
    const float* wq       = (const float*)d_in[9];
    const float* bq       = (const float*)d_in[10];
    const float* wk       = (const float*)d_in[11];
    const float* bk       = (const float*)d_in[12];
    const float* wv       = (const float*)d_in[13];
    const float* bv       = (const float*)d_in[14];
    const float* lepe_w   = (const float*)d_in[15];
    const float* lepe_b   = (const float*)d_in[16];
    const float* wo       = (const float*)d_in[17];
    const float* bo       = (const float*)d_in[18];
    const float* fc1_w    = (const float*)d_in[19];
    const float* fc1_b    = (const float*)d_in[20];
    const float* fc2_w    = (const float*)d_in[21];
    const float* fc2_b    = (const float*)d_in[22];
    const float* pos_w    = (const float*)d_in[23];
    const float* pos_b    = (const float*)d_in[24];
    const float* ca_in_w  = (const float*)d_in[25];
    const float* ca_in_b  = (const float*)d_in[26];
    const float* ca_out_w = (const float*)d_in[27];
    const float* ca_out_b = (const float*)d_in[28];

    float* ws = (float*)d_ws;
    const long SZ = (long)B_ * L_ * E_;       // 2,097,152
    float* X    = ws;                  // f32
    float* Vbf  = ws + SZ;             // f32 V (lepe input)
    float* LEP  = ws + 2 * SZ;         // f32; Q2 alias after main attn
    float* Q2   = LEP;
    ushort_t* U = (ushort_t*)(ws + 3 * SZ);
    // T0 region reused sequentially: HN1 -> ATT -> HN2 -> Xb
    ushort_t* T0    = U;               // [SZ]
    ushort_t* Qb_u  = U + SZ;          // [SZ]
    ushort_t* Kb_u  = U + 2 * SZ;      // [SZ]
    ushort_t* Vb_u  = U + 3 * SZ;      // [SZ]
    ushort_t* HID_u = U + 4 * SZ;      // [4*SZ]; MB alias (mask dead before fc1)
    ushort_t* MB_u  = HID_u;
    ushort_t* WB    = U + 8 * SZ;      // [1,048,576] bf16 weights
    // CA aliases:
    ushort_t* KV_u   = U + SZ;         // 8192x512 spans Qb..Kb (dead after attn)
    ushort_t* QLN_u  = Vb_u;           // Vb_u dead after main attn
    ushort_t* QP_u   = Vb_u + 131072;
    ushort_t* CAO_u  = Vb_u + 262144;
    ushort_t* QHID_u = Vb_u + 393216;  // 512*1024
    // bf16 weight offsets
    ushort_t* wqB    = WB;
    ushort_t* wkB    = WB + 65536;
    ushort_t* wvB    = WB + 131072;
    ushort_t* woB    = WB + 196608;
    ushort_t* fc1B   = WB + 262144;
    ushort_t* fc2B   = WB + 524288;
    ushort_t* cainB  = WB + 786432;
    ushort_t* caoutB = WB + 983040;

    float* XOUT = (float*)d_out;
    float* QOUT = (float*)d_out + 2097152;

    dim3 blk(256);
    const int rows = B_ * L_;  // 8192
    const float* Z = nullptr;

    WTab wt;
    wt.src[0] = wq; wt.src[1] = wk; wt.src[2] = wv; wt.src[3] = wo;
    wt.src[4] = fc1_w; wt.src[5] = fc2_w; wt.src[6] = ca_in_w; wt.src[7] = ca_out_w;

    // ---- prep ----
    wconv_kernel<<<1024, blk, 0, stream>>>(wt, WB);
    maskcvt_kernel<<<8192, blk, 0, stream>>>(mask, MB_u);
    posconv_ln_kernel<<<rows, blk, 0, stream>>>(x, pos_w, pos_b, ln1_g, ln1_b, X, T0);

    // ---- main path ----
    gemm2<0,1><<<dim3(128, 4), blk, 0, stream>>>(T0, wqB, bq, Qb_u, nullptr, Z, rows, 256, 256, 1.0f, 0, sinp, cosp);
    gemm2<0,1><<<dim3(128, 4), blk, 0, stream>>>(T0, wkB, bk, Kb_u, nullptr, Z, rows, 256, 256, SCALING_, 256, sinp, cosp);
    gemm2<0,0><<<dim3(128, 4), blk, 0, stream>>>(T0, wvB, bv, Vb_u, Vbf, Z, rows, 256, 256, 1.0f, 0, Z, Z);
    lepe_kernel<<<rows, blk, 0, stream>>>(Vbf, lepe_w, lepe_b, LEP);
    attn3<<<dim3(16, 8, 8), blk, 0, stream>>>(Qb_u, 256, Kb_u, 256, Vb_u, 256, MB_u, LEP, T0, L_);
    gemm2<0,0><<<dim3(128, 4), blk, 0, stream>>>(T0, woB, bo, nullptr, X, X, rows, 256, 256, 1.0f, 0, Z, Z);
    ln_kernel<<<rows, blk, 0, stream>>>(X, ln2_g, ln2_b, T0);
    gemm2<1,0><<<dim3(128, 16), blk, 0, stream>>>(T0, fc1B, fc1_b, HID_u, nullptr, Z, rows, 1024, 256, 1.0f, 0, Z, Z);
    gemm2<0,0><<<dim3(128, 4), blk, 0, stream>>>(HID_u, fc2B, fc2_b, T0, XOUT, X, rows, 256, 1024, 1.0f, 0, Z, Z);

    // ---- cross-attention path (A = bf16 final x in T0) ----
    ln_kernel<<<B_ * NQ_, blk, 0, stream>>>(queries, ln1_g, ln1_b, QLN_u);
    gemm2<0,0><<<dim3(8, 4), blk, 0, stream>>>(QLN_u, cainB, ca_in_b, QP_u, nullptr, Z, 512, 256, 256, 1.0f, 0, Z, Z);
    gemm2<0,0><<<dim3(128, 8), blk, 0, stream>>>(T0, cainB + 65536, ca_in_b + 256, KV_u, nullptr, Z, rows, 512, 256, SCALING_, 256, Z, Z);
    attn3<<<dim3(1, 8, 8), blk, 0, stream>>>(QP_u, 256, KV_u, 512, KV_u + 256, 512, nullptr, nullptr, CAO_u, NQ_);
    gemm2<0,0><<<dim3(8, 4), blk, 0, stream>>>(CAO_u, caoutB, ca_out_b, nullptr, Q2, queries, 512, 256, 256, 1.0f, 0, Z, Z);
    ln_kernel<<<B_ * NQ_, blk, 0, stream>>>(Q2, ln2_g, ln2_b, QLN_u);
    gemm2<1,0><<<dim3(8, 16), blk, 0, stream>>>(QLN_u, fc1B, fc1_b, QHID_u, nullptr, Z, 512, 1024, 256, 1.0f, 0, Z, Z);
    gemm2<0,0><<<dim3(8, 4), blk, 0, stream>>>(QHID_u, fc2B, fc2_b, nullptr, QOUT, Q2, 512, 256, 1024, 1.0f, 0, Z, Z);
}

// Round 7
// 367.347 us; speedup vs baseline: 1.5422x; 1.1891x over previous
//
#include <hip/hip_runtime.h>
#include <hip/hip_bf16.h>

#define B_      8
#define HH      32
#define WW      32
#define E_      256
#define HEADS_  8
#define KD_     32
#define FFN_    1024
#define NQ_     64
#define L_      1024
#define SCALING_ 0.17677669529663687f
#define EPS_    1e-6f

typedef short bf16x8 __attribute__((ext_vector_type(8)));
typedef float f32x4 __attribute__((ext_vector_type(4)));
typedef unsigned short ushort_t;

__device__ __forceinline__ ushort_t f2bf(float f) {
    __hip_bfloat16 h = __float2bfloat16(f);
    return *reinterpret_cast<ushort_t*>(&h);
}
__device__ __forceinline__ float bf2f(ushort_t u) {
    __hip_bfloat16 h = *reinterpret_cast<__hip_bfloat16*>(&u);
    return __bfloat162float(h);
}

// ---- transpose depthwise weights to [tap][e] ----------------------------
__global__ void dwT_kernel(const float* __restrict__ lepe_w, const float* __restrict__ pos_w,
                           float* __restrict__ LWT, float* __restrict__ PWT) {
    int e = threadIdx.x;
#pragma unroll
    for (int t = 0; t < 25; ++t) LWT[t * 256 + e] = lepe_w[e * 25 + t];
#pragma unroll
    for (int t = 0; t < 9; ++t) PWT[t * 256 + e] = pos_w[e * 9 + t];
}

// ---- fused 3x3 depthwise conv + residual + LN (wave per row) ------------
// grid 2048: b=idx>>8, hh=(idx>>3)&31, wg=idx&7; wave->ww, lane->channel quad
__global__ __launch_bounds__(256) void posconv_ln2(
        const float* __restrict__ x, const float* __restrict__ PWT,
        const float* __restrict__ bias, const float* __restrict__ g,
        const float* __restrict__ bb, float* __restrict__ X, ushort_t* __restrict__ HN) {
    int tid = threadIdx.x;
    int wave = tid >> 6, lane = tid & 63;
    int b = blockIdx.x >> 8, rem = blockIdx.x & 255;
    int hh = rem >> 3, wg = rem & 7;
    int ww = wg * 4 + wave;
    int e = lane * 4;
    long row = ((long)(b * HH + hh)) * WW + ww;

    float4 bi = *reinterpret_cast<const float4*>(bias + e);
    float ax = bi.x, ay = bi.y, az = bi.z, aw = bi.w;
#pragma unroll
    for (int dh = 0; dh < 3; ++dh) {
        int h2 = hh + dh - 1; if (h2 < 0 || h2 >= HH) continue;
        float rx = 0.f, ry = 0.f, rz = 0.f, rw = 0.f;
#pragma unroll
        for (int dw = 0; dw < 3; ++dw) {
            int w2 = ww + dw - 1; if (w2 < 0 || w2 >= WW) continue;
            float4 v = *reinterpret_cast<const float4*>(x + (((long)(b * HH + h2)) * WW + w2) * E_ + e);
            float4 wt = *reinterpret_cast<const float4*>(PWT + (dh * 3 + dw) * 256 + e);
            rx += v.x * wt.x; ry += v.y * wt.y; rz += v.z * wt.z; rw += v.w * wt.w;
        }
        ax += rx; ay += ry; az += rz; aw += rw;
    }
    float4 x4 = *reinterpret_cast<const float4*>(x + row * E_ + e);
    float vx = x4.x + ax, vy = x4.y + ay, vz = x4.z + az, vw = x4.w + aw;
    float4 o4 = {vx, vy, vz, vw};
    *reinterpret_cast<float4*>(X + row * E_ + e) = o4;

    float s = vx + vy + vz + vw;
#pragma unroll
    for (int off = 1; off < 64; off <<= 1) s += __shfl_xor(s, off);
    float mean = s * (1.0f / E_);
    float dx = vx - mean, dy = vy - mean, dz = vz - mean, dw_ = vw - mean;
    float s2 = dx * dx + dy * dy + dz * dz + dw_ * dw_;
#pragma unroll
    for (int off = 1; off < 64; off <<= 1) s2 += __shfl_xor(s2, off);
    float r = rsqrtf(s2 * (1.0f / E_) + EPS_);
    float4 g4 = *reinterpret_cast<const float4*>(g + e);
    float4 b4 = *reinterpret_cast<const float4*>(bb + e);
    uint2 p;
    p.x = (unsigned int)f2bf(dx * r * g4.x + b4.x) | ((unsigned int)f2bf(dy * r * g4.y + b4.y) << 16);
    p.y = (unsigned int)f2bf(dz * r * g4.z + b4.z) | ((unsigned int)f2bf(dw_ * r * g4.w + b4.w) << 16);
    *reinterpret_cast<uint2*>(HN + row * E_ + e) = p;
}

// ---- 5x5 depthwise conv (wave per row, float4) --------------------------
__global__ __launch_bounds__(256) void lepe2(
        const float* __restrict__ v, const float* __restrict__ LWT,
        const float* __restrict__ bias, float* __restrict__ out) {
    int tid = threadIdx.x;
    int wave = tid >> 6, lane = tid & 63;
    int b = blockIdx.x >> 8, rem = blockIdx.x & 255;
    int hh = rem >> 3, wg = rem & 7;
    int ww = wg * 4 + wave;
    int e = lane * 4;
    long row = ((long)(b * HH + hh)) * WW + ww;

    float4 bi = *reinterpret_cast<const float4*>(bias + e);
    float ax = bi.x, ay = bi.y, az = bi.z, aw = bi.w;
#pragma unroll
    for (int dh = 0; dh < 5; ++dh) {
        int h2 = hh + dh - 2; if (h2 < 0 || h2 >= HH) continue;
        float rx = 0.f, ry = 0.f, rz = 0.f, rw = 0.f;
#pragma unroll
        for (int dw = 0; dw < 5; ++dw) {
            int w2 = ww + dw - 2; if (w2 < 0 || w2 >= WW) continue;
            float4 vv = *reinterpret_cast<const float4*>(v + (((long)(b * HH + h2)) * WW + w2) * E_ + e);
            float4 wt = *reinterpret_cast<const float4*>(LWT + (dh * 5 + dw) * 256 + e);
            rx += vv.x * wt.x; ry += vv.y * wt.y; rz += vv.z * wt.z; rw += vv.w * wt.w;
        }
        ax += rx; ay += ry; az += rz; aw += rw;
    }
    float4 o4 = {ax, ay, az, aw};
    *reinterpret_cast<float4*>(out + row * E_ + e) = o4;
}

// ---- LayerNorm v2: wave per row, f32 -> bf16 ----------------------------
__global__ __launch_bounds__(256) void ln2(
        const float* __restrict__ x, const float* __restrict__ g,
        const float* __restrict__ b, ushort_t* __restrict__ y) {
    int tid = threadIdx.x;
    int wave = tid >> 6, lane = tid & 63;
    long row = (long)blockIdx.x * 4 + wave;
    int e = lane * 4;
    float4 v4 = *reinterpret_cast<const float4*>(x + row * E_ + e);
    float s = v4.x + v4.y + v4.z + v4.w;
#pragma unroll
    for (int off = 1; off < 64; off <<= 1) s += __shfl_xor(s, off);
    float mean = s * (1.0f / E_);
    float dx = v4.x - mean, dy = v4.y - mean, dz = v4.z - mean, dw = v4.w - mean;
    float s2 = dx * dx + dy * dy + dz * dz + dw * dw;
#pragma unroll
    for (int off = 1; off < 64; off <<= 1) s2 += __shfl_xor(s2, off);
    float r = rsqrtf(s2 * (1.0f / E_) + EPS_);
    float4 g4 = *reinterpret_cast<const float4*>(g + e);
    float4 b4 = *reinterpret_cast<const float4*>(b + e);
    uint2 p;
    p.x = (unsigned int)f2bf(dx * r * g4.x + b4.x) | ((unsigned int)f2bf(dy * r * g4.y + b4.y) << 16);
    p.y = (unsigned int)f2bf(dz * r * g4.z + b4.z) | ((unsigned int)f2bf(dw * r * g4.w + b4.w) << 16);
    *reinterpret_cast<uint2*>(y + row * E_ + e) = p;
}

// ---- mask f32 -> bf16 (coalesced) ---------------------------------------
__global__ void maskcvt_kernel(const float* __restrict__ m, ushort_t* __restrict__ o) {
    long i = ((long)blockIdx.x * 256 + threadIdx.x) * 4;
    float4 v = *reinterpret_cast<const float4*>(m + i);
    uint2 p;
    p.x = (unsigned int)f2bf(v.x) | ((unsigned int)f2bf(v.y) << 16);
    p.y = (unsigned int)f2bf(v.z) | ((unsigned int)f2bf(v.w) << 16);
    *reinterpret_cast<uint2*>(o + i) = p;
}

// ---- convert all weights to bf16 once -----------------------------------
struct WTab { const float* src[8]; };
__global__ void wconv_kernel(WTab t, ushort_t* __restrict__ dst) {
    const int off[9] = {0, 65536, 131072, 196608, 262144, 524288, 786432, 983040, 1048576};
    long base = ((long)blockIdx.x * 256 + threadIdx.x) * 4;
    int r = 0;
#pragma unroll
    for (int i = 1; i < 8; ++i) r = (base >= off[i]) ? i : r;
    const float* s =
        r == 0 ? t.src[0] : r == 1 ? t.src[1] : r == 2 ? t.src[2] : r == 3 ? t.src[3] :
        r == 4 ? t.src[4] : r == 5 ? t.src[5] : r == 6 ? t.src[6] : t.src[7];
    float4 v = *reinterpret_cast<const float4*>(s + (base - off[r]));
    uint2 p;
    p.x = (unsigned int)f2bf(v.x) | ((unsigned int)f2bf(v.y) << 16);
    p.y = (unsigned int)f2bf(v.z) | ((unsigned int)f2bf(v.w) << 16);
    *reinterpret_cast<uint2*>(dst + base) = p;
}

// ---- MFMA GEMM v2: BM=64 BN=64 BK=64, bf16 A & W, register prefetch -----
template<int ACT, int THETA>
__global__ __launch_bounds__(256) void gemm2(
        const ushort_t* __restrict__ A, const ushort_t* __restrict__ W,
        const float* __restrict__ bias, ushort_t* __restrict__ Cb,
        float* __restrict__ Cf, const float* __restrict__ resid,
        int M, int N, int K, float scale, int scaleN,
        const float* __restrict__ sinp, const float* __restrict__ cosp) {
    __shared__ __align__(16) ushort_t As[64 * 72];
    __shared__ __align__(16) ushort_t Ws[64 * 72];
    int tid = threadIdx.x;
    int wave = tid >> 6, lane = tid & 63;
    int quad = lane >> 4, l16 = lane & 15;
    int wm = wave >> 1, wn = wave & 1;
    long mBase = (long)blockIdx.x * 64;
    long nBase = (long)blockIdx.y * 64;
    int row = tid >> 3, q = tid & 7;
    int row2 = (tid + 256) >> 3, q2 = (tid + 256) & 7;

    f32x4 acc[2][2];
#pragma unroll
    for (int i = 0; i < 2; ++i)
#pragma unroll
        for (int j = 0; j < 2; ++j) acc[i][j] = (f32x4){0.f, 0.f, 0.f, 0.f};

    int nT = K >> 6;
    uint4 a0 = *reinterpret_cast<const uint4*>(A + (mBase + row) * (long)K + q * 8);
    uint4 a1 = *reinterpret_cast<const uint4*>(A + (mBase + row2) * (long)K + q2 * 8);
    uint4 w0 = *reinterpret_cast<const uint4*>(W + (nBase + row) * (long)K + q * 8);
    uint4 w1 = *reinterpret_cast<const uint4*>(W + (nBase + row2) * (long)K + q2 * 8);

    for (int t = 0; t < nT; ++t) {
        *reinterpret_cast<uint4*>(&As[row * 72 + q * 8]) = a0;
        *reinterpret_cast<uint4*>(&As[row2 * 72 + q2 * 8]) = a1;
        *reinterpret_cast<uint4*>(&Ws[row * 72 + q * 8]) = w0;
        *reinterpret_cast<uint4*>(&Ws[row2 * 72 + q2 * 8]) = w1;
        __syncthreads();
        if (t + 1 < nT) {
            int kt = (t + 1) << 6;
            a0 = *reinterpret_cast<const uint4*>(A + (mBase + row) * (long)K + kt + q * 8);
            a1 = *reinterpret_cast<const uint4*>(A + (mBase + row2) * (long)K + kt + q2 * 8);
            w0 = *reinterpret_cast<const uint4*>(W + (nBase + row) * (long)K + kt + q * 8);
            w1 = *reinterpret_cast<const uint4*>(W + (nBase + row2) * (long)K + kt + q2 * 8);
        }
#pragma unroll
        for (int kk = 0; kk < 2; ++kk) {
            bf16x8 af[2], bfr[2];
#pragma unroll
            for (int i = 0; i < 2; ++i)
                af[i] = *reinterpret_cast<const bf16x8*>(&As[(wm * 32 + i * 16 + l16) * 72 + kk * 32 + quad * 8]);
#pragma unroll
            for (int j = 0; j < 2; ++j)
                bfr[j] = *reinterpret_cast<const bf16x8*>(&Ws[(wn * 32 + j * 16 + l16) * 72 + kk * 32 + quad * 8]);
#pragma unroll
            for (int i = 0; i < 2; ++i)
#pragma unroll
                for (int j = 0; j < 2; ++j)
                    acc[i][j] = __builtin_amdgcn_mfma_f32_16x16x32_bf16(af[i], bfr[j], acc[i][j], 0, 0, 0);
        }
        __syncthreads();
    }

#pragma unroll
    for (int i = 0; i < 2; ++i)
#pragma unroll
        for (int j = 0; j < 2; ++j) {
            long n = nBase + wn * 32 + j * 16 + l16;
            float bn = bias[n];
            float eff = (n < scaleN) ? scale : 1.0f;
#pragma unroll
            for (int r = 0; r < 4; ++r) {
                long m = mBase + wm * 32 + i * 16 + quad * 4 + r;
                float v = (acc[i][j][r] + bn) * eff;
                if (THETA) {
                    float other = __shfl_xor(v, 1);
                    int l = (int)(m & (L_ - 1));
                    int d = (int)(n & 31);
                    float cc = cosp[l * 32 + d], ss = sinp[l * 32 + d];
                    v = v * cc + ((n & 1) ? other : -other) * ss;
                }
                if (ACT) v = 0.5f * v * (1.0f + erff(v * 0.70710678118654752f));
                if (resid) v += resid[m * N + n];
                if (Cf) Cf[m * N + n] = v;
                if (Cb) Cb[m * N + n] = f2bf(v);
            }
        }
}

// ---- MFMA flash attention v3: double-buffered Vt, direct mask loads -----
__global__ __launch_bounds__(256) void attn3(
        const ushort_t* __restrict__ Q, int qs,
        const ushort_t* __restrict__ K, int ks,
        const ushort_t* __restrict__ V, int vs,
        const ushort_t* __restrict__ maskbf,
        const float* __restrict__ lepe, ushort_t* __restrict__ out, int nq) {
    __shared__ __align__(16) ushort_t Vt[2][32 * 136];
    __shared__ __align__(16) ushort_t Pl[4][16 * 136];
    int tid = threadIdx.x;
    int wave = tid >> 6, lane = tid & 63;
    int quad = lane >> 4, l16 = lane & 15;
    int qt = blockIdx.x, h = blockIdx.y, b = blockIdx.z;
    int qbase = qt * 64 + wave * 16;

    bf16x8 qfrag = *reinterpret_cast<const bf16x8*>(
        Q + ((long)b * nq + qbase + l16) * qs + h * KD_ + quad * 8);

    f32x4 acc_o[2];
    acc_o[0] = (f32x4){0.f, 0.f, 0.f, 0.f};
    acc_o[1] = (f32x4){0.f, 0.f, 0.f, 0.f};
    float lsum[4] = {0.f, 0.f, 0.f, 0.f};

    int kp = tid & 63;
    int dq = tid >> 6;

    const ushort_t* vp = V + ((long)b * L_ + 2 * kp) * vs + h * KD_ + dq * 8;
    uint4 ua = *reinterpret_cast<const uint4*>(vp);
    uint4 ub = *reinterpret_cast<const uint4*>(vp + vs);
    {
        const unsigned int* wa = reinterpret_cast<const unsigned int*>(&ua);
        const unsigned int* wb = reinterpret_cast<const unsigned int*>(&ub);
#pragma unroll
        for (int i = 0; i < 8; ++i) {
            unsigned int x16 = (wa[i >> 1] >> ((i & 1) * 16)) & 0xFFFF;
            unsigned int y16 = (wb[i >> 1] >> ((i & 1) * 16)) & 0xFFFF;
            *reinterpret_cast<unsigned int*>(&Vt[0][(dq * 8 + i) * 136 + 2 * kp]) =
                x16 | (y16 << 16);
        }
    }

    for (int it = 0; it < 8; ++it) {
        int kb = it * 128;
        __syncthreads();
        if (it < 7) {
            const ushort_t* vn = V + ((long)b * L_ + kb + 128 + 2 * kp) * vs + h * KD_ + dq * 8;
            ua = *reinterpret_cast<const uint4*>(vn);
            ub = *reinterpret_cast<const uint4*>(vn + vs);
        }

#pragma unroll
        for (int g = 0; g < 2; ++g) {
            bf16x8 kf[4];
#pragma unroll
            for (int kt = 0; kt < 4; ++kt)
                kf[kt] = *reinterpret_cast<const bf16x8*>(
                    K + ((long)b * L_ + kb + (g * 4 + kt) * 16 + l16) * ks + h * KD_ + quad * 8);
#pragma unroll
            for (int kt = 0; kt < 4; ++kt) {
                int kcol = (g * 4 + kt) * 16;
                f32x4 sa;
                if (maskbf) {
#pragma unroll
                    for (int r = 0; r < 4; ++r)
                        sa[r] = bf2f(maskbf[((long)h * L_ + qbase + quad * 4 + r) * L_ + kb + kcol + l16]);
                } else {
                    sa = (f32x4){0.f, 0.f, 0.f, 0.f};
                }
                sa = __builtin_amdgcn_mfma_f32_16x16x32_bf16(qfrag, kf[kt], sa, 0, 0, 0);
#pragma unroll
                for (int r = 0; r < 4; ++r) {
                    float p = __expf(sa[r]);
                    lsum[r] += p;
                    Pl[wave][(quad * 4 + r) * 136 + kcol + l16] = f2bf(p);
                }
            }
        }

#pragma unroll
        for (int c = 0; c < 4; ++c) {
            bf16x8 pa = *reinterpret_cast<const bf16x8*>(
                &Pl[wave][l16 * 136 + c * 32 + quad * 8]);
#pragma unroll
            for (int dt = 0; dt < 2; ++dt) {
                bf16x8 vf = *reinterpret_cast<const bf16x8*>(
                    &Vt[it & 1][(dt * 16 + l16) * 136 + c * 32 + quad * 8]);
                acc_o[dt] = __builtin_amdgcn_mfma_f32_16x16x32_bf16(pa, vf, acc_o[dt], 0, 0, 0);
            }
        }

        if (it < 7) {
            const unsigned int* wa = reinterpret_cast<const unsigned int*>(&ua);
            const unsigned int* wb = reinterpret_cast<const unsigned int*>(&ub);
#pragma unroll
            for (int i = 0; i < 8; ++i) {
                unsigned int x16 = (wa[i >> 1] >> ((i & 1) * 16)) & 0xFFFF;
                unsigned int y16 = (wb[i >> 1] >> ((i & 1) * 16)) & 0xFFFF;
                *reinterpret_cast<unsigned int*>(&Vt[(it + 1) & 1][(dq * 8 + i) * 136 + 2 * kp]) =
                    x16 | (y16 << 16);
            }
        }
    }

#pragma unroll
    for (int off = 1; off < 16; off <<= 1) {
#pragma unroll
        for (int r = 0; r < 4; ++r) lsum[r] += __shfl_xor(lsum[r], off);
    }

#pragma unroll
    for (int dt = 0; dt < 2; ++dt)
#pragma unroll
        for (int r = 0; r < 4; ++r) {
            float v = acc_o[dt][r] / lsum[r];
            long oi = ((long)b * nq + qbase + quad * 4 + r) * E_ + h * KD_ + dt * 16 + l16;
            if (lepe) v += lepe[oi];
            out[oi] = f2bf(v);
        }
}

extern "C" void kernel_launch(void* const* d_in, const int* in_sizes, int n_in,
                              void* d_out, int out_size, void* d_ws, size_t ws_size,
                              hipStream_t stream) {
    const float* x        = (const float*)d_in[0];
    const float* queries  = (const float*)d_in[1];
    const float* sinp     = (const float*)d_in[2];
    const float* cosp     = (const float*)d_in[3];
    const float* mask     = (const float*)d_in[4];
    const float* ln1_g    = (const float*)d_in[5];
    const float* ln1_b    = (const float*)d_in[6];
    const float* ln2_g    = (const float*)d_in[7];
    const float* ln2_b    = (const float*)d_in[8];
    const float* wq       = (const float*)d_in[9];
    const float* bq       = (const float*)d_in[10];
    const float* wk       = (const float*)d_in[11];
    const float* bk       = (const float*)d_in[12];
    const float* wv       = (const float*)d_in[13];
    const float* bv       = (const float*)d_in[14];
    const float* lepe_w   = (const float*)d_in[15];
    const float* lepe_b   = (const float*)d_in[16];
    const float* wo       = (const float*)d_in[17];
    const float* bo       = (const float*)d_in[18];
    const float* fc1_w    = (const float*)d_in[19];
    const float* fc1_b    = (const float*)d_in[20];
    const float* fc2_w    = (const float*)d_in[21];
    const float* fc2_b    = (const float*)d_in[22];
    const float* pos_w    = (const float*)d_in[23];
    const float* pos_b    = (const float*)d_in[24];
    const float* ca_in_w  = (const float*)d_in[25];
    const float* ca_in_b  = (const float*)d_in[26];
    const float* ca_out_w = (const float*)d_in[27];
    const float* ca_out_b = (const float*)d_in[28];

    float* ws = (float*)d_ws;
    const long SZ = (long)B_ * L_ * E_;       // 2,097,152
    float* X    = ws;
    float* Vbf  = ws + SZ;
    float* LEP  = ws + 2 * SZ;
    float* Q2   = LEP;
    ushort_t* U = (ushort_t*)(ws + 3 * SZ);
    ushort_t* T0    = U;               // HN1 -> ATT -> HN2 -> Xb
    ushort_t* Qb_u  = U + SZ;
    ushort_t* Kb_u  = U + 2 * SZ;
    ushort_t* Vb_u  = U + 3 * SZ;
    ushort_t* HID_u = U + 4 * SZ;      // 4*SZ; MB alias
    ushort_t* MB_u  = HID_u;
    ushort_t* WB    = U + 8 * SZ;      // bf16 weights [1,048,576]
    float* LWT      = (float*)(WB + 1048576);   // 25*256 f32
    float* PWT      = LWT + 6400;               // 9*256 f32
    // CA aliases:
    ushort_t* KV_u   = U + SZ;
    ushort_t* QLN_u  = Vb_u;
    ushort_t* QP_u   = Vb_u + 131072;
    ushort_t* CAO_u  = Vb_u + 262144;
    ushort_t* QHID_u = Vb_u + 393216;
    ushort_t* wqB    = WB;
    ushort_t* wkB    = WB + 65536;
    ushort_t* wvB    = WB + 131072;
    ushort_t* woB    = WB + 196608;
    ushort_t* fc1B   = WB + 262144;
    ushort_t* fc2B   = WB + 524288;
    ushort_t* cainB  = WB + 786432;
    ushort_t* caoutB = WB + 983040;

    float* XOUT = (float*)d_out;
    float* QOUT = (float*)d_out + 2097152;

    dim3 blk(256);
    const int rows = B_ * L_;  // 8192
    const float* Z = nullptr;

    WTab wt;
    wt.src[0] = wq; wt.src[1] = wk; wt.src[2] = wv; wt.src[3] = wo;
    wt.src[4] = fc1_w; wt.src[5] = fc2_w; wt.src[6] = ca_in_w; wt.src[7] = ca_out_w;

    // ---- prep ----
    dwT_kernel<<<1, blk, 0, stream>>>(lepe_w, pos_w, LWT, PWT);
    wconv_kernel<<<1024, blk, 0, stream>>>(wt, WB);
    maskcvt_kernel<<<8192, blk, 0, stream>>>(mask, MB_u);
    posconv_ln2<<<2048, blk, 0, stream>>>(x, PWT, pos_b, ln1_g, ln1_b, X, T0);

    // ---- main path ----
    gemm2<0,1><<<dim3(128, 4), blk, 0, stream>>>(T0, wqB, bq, Qb_u, nullptr, Z, rows, 256, 256, 1.0f, 0, sinp, cosp);
    gemm2<0,1><<<dim3(128, 4), blk, 0, stream>>>(T0, wkB, bk, Kb_u, nullptr, Z, rows, 256, 256, SCALING_, 256, sinp, cosp);
    gemm2<0,0><<<dim3(128, 4), blk, 0, stream>>>(T0, wvB, bv, Vb_u, Vbf, Z, rows, 256, 256, 1.0f, 0, Z, Z);
    lepe2<<<2048, blk, 0, stream>>>(Vbf, LWT, lepe_b, LEP);
    attn3<<<dim3(16, 8, 8), blk, 0, stream>>>(Qb_u, 256, Kb_u, 256, Vb_u, 256, MB_u, LEP, T0, L_);
    gemm2<0,0><<<dim3(128, 4), blk, 0, stream>>>(T0, woB, bo, nullptr, X, X, rows, 256, 256, 1.0f, 0, Z, Z);
    ln2<<<2048, blk, 0, stream>>>(X, ln2_g, ln2_b, T0);
    gemm2<1,0><<<dim3(128, 16), blk, 0, stream>>>(T0, fc1B, fc1_b, HID_u, nullptr, Z, rows, 1024, 256, 1.0f, 0, Z, Z);
    gemm2<0,0><<<dim3(128, 4), blk, 0, stream>>>(HID_u, fc2B, fc2_b, T0, XOUT, X, rows, 256, 1024, 1.0f, 0, Z, Z);

    // ---- cross-attention path (A = bf16 final x in T0) ----
    ln2<<<128, blk, 0, stream>>>(queries, ln1_g, ln1_b, QLN_u);
    gemm2<0,0><<<dim3(8, 4), blk, 0, stream>>>(QLN_u, cainB, ca_in_b, QP_u, nullptr, Z, 512, 256, 256, 1.0f, 0, Z, Z);
    gemm2<0,0><<<dim3(128, 8), blk, 0, stream>>>(T0, cainB + 65536, ca_in_b + 256, KV_u, nullptr, Z, rows, 512, 256, SCALING_, 256, Z, Z);
    attn3<<<dim3(1, 8, 8), blk, 0, stream>>>(QP_u, 256, KV_u, 512, KV_u + 256, 512, nullptr, nullptr, CAO_u, NQ_);
    gemm2<0,0><<<dim3(8, 4), blk, 0, stream>>>(CAO_u, caoutB, ca_out_b, nullptr, Q2, queries, 512, 256, 256, 1.0f, 0, Z, Z);
    ln2<<<128, blk, 0, stream>>>(Q2, ln2_g, ln2_b, QLN_u);
    gemm2<1,0><<<dim3(8, 16), blk, 0, stream>>>(QLN_u, fc1B, fc1_b, QHID_u, nullptr, Z, 512, 1024, 256, 1.0f, 0, Z, Z);
    gemm2<0,0><<<dim3(8, 4), blk, 0, stream>>>(QHID_u, fc2B, fc2_b, nullptr, QOUT, Q2, 512, 256, 1024, 1.0f, 0, Z, Z);
}